// Round 6
// baseline (411.877 us; speedup 1.0000x reference)
//
#include <hip/hip_runtime.h>
#include <math.h>

#define NN 4096
#define NB 4
#define MSPLIT 16          // column slabs (also number of T-build slabs)
#define MSLAB 256          // NN / MSPLIT
#define NITER 10

// persistent scratch in module .bss — fully rewritten every call (deterministic)
__device__ __align__(16) float gA [NB * NN];
__device__ __align__(16) float gUx[NB * NN];
__device__ __align__(16) float gUy[NB * NN];
__device__ __align__(16) float gT[2][NN][12];        // ping-pong T vectors
__device__ __align__(16) float gY[MSPLIT][NN][12];   // per-slab partials
__device__ int gCnt[MSPLIT];                          // last-block counters

__device__ inline unsigned bf16r(float x) {          // RTNE f32 -> bf16 bits
    unsigned u = __float_as_uint(x);
    return (u + 0x7fffu + ((u >> 16) & 1u)) >> 16;
}

// ---- stats + T(iter0) + counter init ----
__global__ __launch_bounds__(256) void stats_kernel(const float* __restrict__ dp,
                                                    const float* __restrict__ logits) {
    int i = blockIdx.x * 256 + threadIdx.x;          // 0..16383
    int b = i >> 12, n = i & 4095;
    float x = dp[2 * i], y = dp[2 * i + 1];
    float sq = x * x + y * y;
    float av = expf(-0.5f * sq);
    float inv = 1.0f / sqrtf(sq);
    float uxv = x * inv, uyv = y * inv;
    gA[i] = av; gUx[i] = uxv; gUy[i] = uyv;
    float l = logits[i];
    float mv = 2.0f / (1.0f + expf(-l)) - 1.0f;
    float t0 = av * mv;
    float* t = &gT[0][n][b * 3];
    t[0] = t0; t[1] = t0 * uxv; t[2] = t0 * uyv;
    if (blockIdx.x == 0 && threadIdx.x < MSPLIT) gCnt[threadIdx.x] = 0;
}

// ---- W_sym = (W+W^T)/2 -> packed bf16 pairs; triangular tile pairs ----
__global__ __launch_bounds__(256) void wsym_kernel(const float* __restrict__ W,
                                                   unsigned* __restrict__ Sb) {
    __shared__ float At[64][65];
    __shared__ float Bt[64][65];
    int idx = blockIdx.x, bi = 0, rem = 64;
    while (idx >= rem) { idx -= rem; ++bi; --rem; }
    int bj = bi + idx;
    int tx = threadIdx.x & 63, ty = threadIdx.x >> 6;
#pragma unroll
    for (int i = 0; i < 16; ++i) {
        int r = ty + i * 4;
        At[r][tx] = W[(size_t)(bi * 64 + r) * NN + bj * 64 + tx];
        Bt[r][tx] = W[(size_t)(bj * 64 + r) * NN + bi * 64 + tx];
    }
    __syncthreads();
    int tp = threadIdx.x & 31;                       // column-pair index
    int rr = threadIdx.x >> 5;                       // 0..7
#pragma unroll
    for (int i = 0; i < 8; ++i) {
        int r = rr + i * 8;
        int c0 = 2 * tp, c1 = c0 + 1;
        float v0 = 0.5f * (At[r][c0] + Bt[c0][r]);
        float v1 = 0.5f * (At[r][c1] + Bt[c1][r]);
        Sb[(size_t)(bi * 64 + r) * 2048 + bj * 32 + tp] = bf16r(v0) | (bf16r(v1) << 16);
        float u0 = 0.5f * (Bt[r][c0] + At[c0][r]);
        float u1 = 0.5f * (Bt[r][c1] + At[c1][r]);
        Sb[(size_t)(bj * 64 + r) * 2048 + bi * 32 + tp] = bf16r(u0) | (bf16r(u1) << 16);
    }
}

// ---- matvec: Y[by][rows] = Wsym[rows, slab] @ T[slab]; last block per T-slab
//      builds next iteration's T. ----
__global__ __launch_bounds__(256, 4) void matvec_kernel(const unsigned* __restrict__ Wb,
    const float* __restrict__ logits, int rd, int last) {
    __shared__ float4 Tp[3][MSLAB];                  // 12 KB
    __shared__ __align__(16) float red[64 * 4 * 12]; // 12 KB
    __shared__ int amLast;

    const int tid = threadIdx.x;
    const int mb = blockIdx.y * MSLAB;

    // stage this slab's T into LDS (swizzled)
    {
        const float4* src = (const float4*)&gT[rd][mb + tid][0];
        float4 a = src[0], b = src[1], c = src[2];
        int sm = tid ^ ((tid >> 3) & 7);
        Tp[0][sm] = a; Tp[1][sm] = b; Tp[2][sm] = c;
    }
    __syncthreads();

    const int lane = tid & 63, wid = tid >> 6;
    const int g = lane >> 4, s = lane & 15;
    const int row0 = blockIdx.x * 64 + wid * 16 + g * 4;
    const unsigned* Wr = Wb + (size_t)row0 * 2048 + (mb >> 1);

    // preload all weights: 2 chunks x 4 rows x uint4 (8 bf16 each)
    uint4 w[2][4];
#pragma unroll
    for (int ch = 0; ch < 2; ++ch)
#pragma unroll
        for (int r = 0; r < 4; ++r)
            w[ch][r] = *(const uint4*)(Wr + (size_t)r * 2048 + ch * 64 + s * 4);

    float acc[4][12];
#pragma unroll
    for (int r = 0; r < 4; ++r)
#pragma unroll
        for (int c = 0; c < 12; ++c) acc[r][c] = 0.f;

#pragma unroll
    for (int ch = 0; ch < 2; ++ch) {
#pragma unroll
        for (int j = 0; j < 8; ++j) {
            int mj = ch * 128 + s * 8 + j;
            int sm = mj ^ ((mj >> 3) & 7);
            float4 t0 = Tp[0][sm], t1 = Tp[1][sm], t2 = Tp[2][sm];
            float tv[12] = {t0.x, t0.y, t0.z, t0.w, t1.x, t1.y, t1.z, t1.w,
                            t2.x, t2.y, t2.z, t2.w};
            float wv[4];
#pragma unroll
            for (int r = 0; r < 4; ++r) {
                unsigned u = (&w[ch][r].x)[j >> 1];
                wv[r] = __uint_as_float((j & 1) ? (u & 0xffff0000u) : (u << 16));
            }
#pragma unroll
            for (int r = 0; r < 4; ++r)
#pragma unroll
                for (int c = 0; c < 12; ++c) acc[r][c] += wv[r] * tv[c];
        }
    }

    // reduce 16 lanes -> 1: 2 shuffle steps + 4-way LDS
#pragma unroll
    for (int mask = 1; mask <= 2; mask <<= 1)
#pragma unroll
        for (int r = 0; r < 4; ++r)
#pragma unroll
            for (int c = 0; c < 12; ++c) acc[r][c] += __shfl_xor(acc[r][c], mask, 64);

    if ((s & 3) == 0) {
        int sub = s >> 2;
#pragma unroll
        for (int r = 0; r < 4; ++r) {
            int rl = wid * 16 + g * 4 + r;
            float4* dst = (float4*)&red[(rl * 4 + sub) * 12];
            dst[0] = make_float4(acc[r][0], acc[r][1], acc[r][2],  acc[r][3]);
            dst[1] = make_float4(acc[r][4], acc[r][5], acc[r][6],  acc[r][7]);
            dst[2] = make_float4(acc[r][8], acc[r][9], acc[r][10], acc[r][11]);
        }
    }
    __syncthreads();

    {
        int rl = tid >> 2, c0 = (tid & 3) * 3;
        float s0 = 0.f, s1 = 0.f, s2 = 0.f;
#pragma unroll
        for (int sub = 0; sub < 4; ++sub) {
            const float* p = &red[(rl * 4 + sub) * 12 + c0];
            s0 += p[0]; s1 += p[1]; s2 += p[2];
        }
        int row = blockIdx.x * 64 + rl;
        float* dst = &gY[blockIdx.y][row][c0];
        __hip_atomic_store(dst + 0, s0, __ATOMIC_RELAXED, __HIP_MEMORY_SCOPE_AGENT);
        __hip_atomic_store(dst + 1, s1, __ATOMIC_RELAXED, __HIP_MEMORY_SCOPE_AGENT);
        __hip_atomic_store(dst + 2, s2, __ATOMIC_RELAXED, __HIP_MEMORY_SCOPE_AGENT);
    }
    __syncthreads();   // drains vmcnt(0) for all threads' Y stores

    if (last) return;

    if (tid == 0) {
        int prev = __hip_atomic_fetch_add(&gCnt[blockIdx.x >> 2], 1,
                                          __ATOMIC_ACQ_REL, __HIP_MEMORY_SCOPE_AGENT);
        amLast = (prev == 63);
    }
    __syncthreads();
    if (!amLast) return;

    // this block is the 64th arriver for T-slab ts: build next T
    __threadfence();
    int ts = blockIdx.x >> 2;
    int m = ts * 256 + tid;
    float S12[12];
#pragma unroll
    for (int c = 0; c < 12; ++c) S12[c] = 0.f;
#pragma unroll
    for (int sl = 0; sl < MSPLIT; ++sl) {
        const float* yp = &gY[sl][m][0];
#pragma unroll
        for (int c = 0; c < 12; ++c)
            S12[c] += __hip_atomic_load(yp + c, __ATOMIC_RELAXED, __HIP_MEMORY_SCOPE_AGENT);
    }
    float outv[12];
#pragma unroll
    for (int b = 0; b < NB; ++b) {
        int idx = b * NN + m;
        float av = gA[idx], uxv = gUx[idx], uyv = gUy[idx];
        float l = logits[idx] +
                  av * (S12[b * 3] - uxv * S12[b * 3 + 1] - uyv * S12[b * 3 + 2]);
        float mv = 2.0f / (1.0f + expf(-l)) - 1.0f;
        float t0 = av * mv;
        outv[b * 3] = t0; outv[b * 3 + 1] = t0 * uxv; outv[b * 3 + 2] = t0 * uyv;
    }
    float4* d = (float4*)&gT[rd ^ 1][m][0];
    d[0] = make_float4(outv[0], outv[1], outv[2],  outv[3]);
    d[1] = make_float4(outv[4], outv[5], outv[6],  outv[7]);
    d[2] = make_float4(outv[8], outv[9], outv[10], outv[11]);
    if (tid == 0) gCnt[ts] = 0;                      // ready for next dispatch
}

// ---- final: out = logits + a*(S0 - ux*S1 - uy*S2) ----
__global__ __launch_bounds__(256) void final_kernel(const float* __restrict__ logits,
                                                    float* __restrict__ out) {
    int m = blockIdx.x * 256 + threadIdx.x;          // 0..4095
    float S12[12];
#pragma unroll
    for (int c = 0; c < 12; ++c) S12[c] = 0.f;
#pragma unroll 4
    for (int sl = 0; sl < MSPLIT; ++sl) {
        const float4* p = (const float4*)&gY[sl][m][0];
        float4 x = p[0], y = p[1], z = p[2];
        S12[0] += x.x; S12[1] += x.y; S12[2]  += x.z; S12[3]  += x.w;
        S12[4] += y.x; S12[5] += y.y; S12[6]  += y.z; S12[7]  += y.w;
        S12[8] += z.x; S12[9] += z.y; S12[10] += z.z; S12[11] += z.w;
    }
#pragma unroll
    for (int b = 0; b < NB; ++b) {
        int idx = b * NN + m;
        out[idx] = logits[idx] +
                   gA[idx] * (S12[b * 3] - gUx[idx] * S12[b * 3 + 1] - gUy[idx] * S12[b * 3 + 2]);
    }
}

extern "C" void kernel_launch(void* const* d_in, const int* in_sizes, int n_in,
                              void* d_out, int out_size, void* d_ws, size_t ws_size,
                              hipStream_t stream) {
    const float* delta_p = (const float*)d_in[0];   // (4,64,64,2)
    const float* logits  = (const float*)d_in[1];   // (4,4096,1)
    const float* W       = (const float*)d_in[2];   // (1,4096,4096)
    float* out = (float*)d_out;

    unsigned* Wb = (unsigned*)d_ws;                  // 32 MiB packed bf16 Wsym

    stats_kernel<<<64, 256, 0, stream>>>(delta_p, logits);
    wsym_kernel<<<2080, 256, 0, stream>>>(W, Wb);    // 64*65/2 triangular tile pairs

    for (int it = 0; it < NITER; ++it)
        matvec_kernel<<<dim3(64, MSPLIT), 256, 0, stream>>>(Wb, logits, it & 1,
                                                            it == NITER - 1 ? 1 : 0);
    final_kernel<<<16, 256, 0, stream>>>(logits, out);
}

// Round 7
// 196.022 us; speedup vs baseline: 2.1012x; 2.1012x over previous
//
#include <hip/hip_runtime.h>
#include <math.h>

#define NN 4096
#define NB 4
#define MSPLIT 16          // column slabs
#define MSLAB 256          // NN / MSPLIT
#define NITER 10

// persistent scratch in module .bss — fully rewritten every call (deterministic)
__device__ __align__(16) float gA [NB * NN];
__device__ __align__(16) float gUx[NB * NN];
__device__ __align__(16) float gUy[NB * NN];
__device__ __align__(16) float gT[NN][12];           // current T vectors
__device__ __align__(16) float gY[MSPLIT][NN][12];   // per-slab partials

__device__ inline unsigned bf16r(float x) {          // RTNE f32 -> bf16 bits
    unsigned u = __float_as_uint(x);
    return (u + 0x7fffu + ((u >> 16) & 1u)) >> 16;
}

// ---- stats + T(iter0) ----
__global__ __launch_bounds__(256) void stats_kernel(const float* __restrict__ dp,
                                                    const float* __restrict__ logits) {
    int i = blockIdx.x * 256 + threadIdx.x;          // 0..16383
    int b = i >> 12, n = i & 4095;
    float x = dp[2 * i], y = dp[2 * i + 1];
    float sq = x * x + y * y;
    float av = expf(-0.5f * sq);
    float inv = 1.0f / sqrtf(sq);
    float uxv = x * inv, uyv = y * inv;
    gA[i] = av; gUx[i] = uxv; gUy[i] = uyv;
    float l = logits[i];
    float mv = 2.0f / (1.0f + expf(-l)) - 1.0f;
    float t0 = av * mv;
    float* t = &gT[n][b * 3];
    t[0] = t0; t[1] = t0 * uxv; t[2] = t0 * uyv;
}

// ---- W_sym = (W+W^T)/2 -> packed bf16 pairs; triangular tile pairs ----
__global__ __launch_bounds__(256) void wsym_kernel(const float* __restrict__ W,
                                                   unsigned* __restrict__ Sb) {
    __shared__ float At[64][65];
    __shared__ float Bt[64][65];
    int idx = blockIdx.x, bi = 0, rem = 64;
    while (idx >= rem) { idx -= rem; ++bi; --rem; }
    int bj = bi + idx;
    int tx = threadIdx.x & 63, ty = threadIdx.x >> 6;
#pragma unroll
    for (int i = 0; i < 16; ++i) {
        int r = ty + i * 4;
        At[r][tx] = W[(size_t)(bi * 64 + r) * NN + bj * 64 + tx];
        Bt[r][tx] = W[(size_t)(bj * 64 + r) * NN + bi * 64 + tx];
    }
    __syncthreads();
    int tp = threadIdx.x & 31;                       // column-pair index
    int rr = threadIdx.x >> 5;                       // 0..7
#pragma unroll
    for (int i = 0; i < 8; ++i) {
        int r = rr + i * 8;
        int c0 = 2 * tp, c1 = c0 + 1;
        float v0 = 0.5f * (At[r][c0] + Bt[c0][r]);
        float v1 = 0.5f * (At[r][c1] + Bt[c1][r]);
        Sb[(size_t)(bi * 64 + r) * 2048 + bj * 32 + tp] = bf16r(v0) | (bf16r(v1) << 16);
        float u0 = 0.5f * (Bt[r][c0] + At[c0][r]);
        float u1 = 0.5f * (Bt[r][c1] + At[c1][r]);
        Sb[(size_t)(bj * 64 + r) * 2048 + bi * 32 + tp] = bf16r(u0) | (bf16r(u1) << 16);
    }
}

// ---- matvec: gY[by][rows] = Wsym[rows, slab] @ gT[slab]  (pure, no atomics) ----
__global__ __launch_bounds__(256, 2) void matvec_kernel(const unsigned* __restrict__ Wb) {
    __shared__ float4 Tp[3][MSLAB];                  // 12 KB
    __shared__ __align__(16) float red[64 * 4 * 12]; // 12 KB

    const int tid = threadIdx.x;
    const int mb = blockIdx.y * MSLAB;

    // stage this slab's T into LDS (swizzled float4 index)
    {
        const float4* src = (const float4*)&gT[mb + tid][0];
        float4 a = src[0], b = src[1], c = src[2];
        int sm = tid ^ ((tid >> 3) & 7);
        Tp[0][sm] = a; Tp[1][sm] = b; Tp[2][sm] = c;
    }
    __syncthreads();

    const int lane = tid & 63, wid = tid >> 6;
    const int g = lane >> 4, s = lane & 15;
    const int row0 = blockIdx.x * 64 + wid * 16 + g * 4;
    const uint2* Wr2 = (const uint2*)(Wb + (size_t)row0 * 2048 + (mb >> 1));

    float acc[4][12];
#pragma unroll
    for (int r = 0; r < 4; ++r)
#pragma unroll
        for (int c = 0; c < 12; ++c) acc[r][c] = 0.f;

#pragma unroll
    for (int ch = 0; ch < 4; ++ch) {
        uint2 w2[4];
#pragma unroll
        for (int r = 0; r < 4; ++r) w2[r] = Wr2[(size_t)r * 1024 + ch * 16 + s];
#pragma unroll
        for (int j = 0; j < 4; ++j) {
            int mj = ch * 64 + s * 4 + j;
            int sm = mj ^ ((mj >> 3) & 7);           // lanes spread 8 bank-groups, 2-way
            float4 t0 = Tp[0][sm], t1 = Tp[1][sm], t2 = Tp[2][sm];
            float tv[12] = {t0.x, t0.y, t0.z, t0.w, t1.x, t1.y, t1.z, t1.w,
                            t2.x, t2.y, t2.z, t2.w};
#pragma unroll
            for (int r = 0; r < 4; ++r) {
                unsigned u = (j >> 1) ? w2[r].y : w2[r].x;
                float wv = __uint_as_float((j & 1) ? (u & 0xffff0000u) : (u << 16));
#pragma unroll
                for (int c = 0; c < 12; ++c) acc[r][c] += wv * tv[c];
            }
        }
    }

    // reduce 16 lanes -> 1: 2 shuffle steps + 4-way LDS
#pragma unroll
    for (int mask = 1; mask <= 2; mask <<= 1)
#pragma unroll
        for (int r = 0; r < 4; ++r)
#pragma unroll
            for (int c = 0; c < 12; ++c) acc[r][c] += __shfl_xor(acc[r][c], mask, 64);

    if ((s & 3) == 0) {
        int sub = s >> 2;
#pragma unroll
        for (int r = 0; r < 4; ++r) {
            int rl = wid * 16 + g * 4 + r;
            float4* dst = (float4*)&red[(rl * 4 + sub) * 12];
            dst[0] = make_float4(acc[r][0], acc[r][1], acc[r][2],  acc[r][3]);
            dst[1] = make_float4(acc[r][4], acc[r][5], acc[r][6],  acc[r][7]);
            dst[2] = make_float4(acc[r][8], acc[r][9], acc[r][10], acc[r][11]);
        }
    }
    __syncthreads();

    {
        int rl = tid >> 2, c0 = (tid & 3) * 3;
        float s0 = 0.f, s1 = 0.f, s2 = 0.f;
#pragma unroll
        for (int sub = 0; sub < 4; ++sub) {
            const float* p = &red[(rl * 4 + sub) * 12 + c0];
            s0 += p[0]; s1 += p[1]; s2 += p[2];
        }
        int row = blockIdx.x * 64 + rl;
        float* dst = &gY[blockIdx.y][row][c0];
        dst[0] = s0; dst[1] = s1; dst[2] = s2;       // plain stores
    }
}

// ---- update: T <- f(logits + a*(combine gY)) ; 16 blocks, vectorized ----
__global__ __launch_bounds__(256) void update_kernel(const float* __restrict__ logits) {
    int m = blockIdx.x * 256 + threadIdx.x;          // 0..4095
    float S12[12];
#pragma unroll
    for (int c = 0; c < 12; ++c) S12[c] = 0.f;
#pragma unroll 4
    for (int sl = 0; sl < MSPLIT; ++sl) {
        const float4* p = (const float4*)&gY[sl][m][0];
        float4 x = p[0], y = p[1], z = p[2];
        S12[0] += x.x; S12[1] += x.y; S12[2]  += x.z; S12[3]  += x.w;
        S12[4] += y.x; S12[5] += y.y; S12[6]  += y.z; S12[7]  += y.w;
        S12[8] += z.x; S12[9] += z.y; S12[10] += z.z; S12[11] += z.w;
    }
    float vals[12];
#pragma unroll
    for (int b = 0; b < NB; ++b) {
        int idx = b * NN + m;
        float av = gA[idx], uxv = gUx[idx], uyv = gUy[idx];
        float l = logits[idx] +
                  av * (S12[b * 3] - uxv * S12[b * 3 + 1] - uyv * S12[b * 3 + 2]);
        float mv = 2.0f / (1.0f + expf(-l)) - 1.0f;
        float t0 = av * mv;
        vals[b * 3] = t0; vals[b * 3 + 1] = t0 * uxv; vals[b * 3 + 2] = t0 * uyv;
    }
    float4* d = (float4*)&gT[m][0];
    d[0] = make_float4(vals[0], vals[1], vals[2],  vals[3]);
    d[1] = make_float4(vals[4], vals[5], vals[6],  vals[7]);
    d[2] = make_float4(vals[8], vals[9], vals[10], vals[11]);
}

// ---- final: out = logits + a*(S0 - ux*S1 - uy*S2) ----
__global__ __launch_bounds__(256) void final_kernel(const float* __restrict__ logits,
                                                    float* __restrict__ out) {
    int m = blockIdx.x * 256 + threadIdx.x;          // 0..4095
    float S12[12];
#pragma unroll
    for (int c = 0; c < 12; ++c) S12[c] = 0.f;
#pragma unroll 4
    for (int sl = 0; sl < MSPLIT; ++sl) {
        const float4* p = (const float4*)&gY[sl][m][0];
        float4 x = p[0], y = p[1], z = p[2];
        S12[0] += x.x; S12[1] += x.y; S12[2]  += x.z; S12[3]  += x.w;
        S12[4] += y.x; S12[5] += y.y; S12[6]  += y.z; S12[7]  += y.w;
        S12[8] += z.x; S12[9] += z.y; S12[10] += z.z; S12[11] += z.w;
    }
#pragma unroll
    for (int b = 0; b < NB; ++b) {
        int idx = b * NN + m;
        out[idx] = logits[idx] +
                   gA[idx] * (S12[b * 3] - gUx[idx] * S12[b * 3 + 1] - gUy[idx] * S12[b * 3 + 2]);
    }
}

extern "C" void kernel_launch(void* const* d_in, const int* in_sizes, int n_in,
                              void* d_out, int out_size, void* d_ws, size_t ws_size,
                              hipStream_t stream) {
    const float* delta_p = (const float*)d_in[0];   // (4,64,64,2)
    const float* logits  = (const float*)d_in[1];   // (4,4096,1)
    const float* W       = (const float*)d_in[2];   // (1,4096,4096)
    float* out = (float*)d_out;

    unsigned* Wb = (unsigned*)d_ws;                  // 32 MiB packed bf16 Wsym

    stats_kernel<<<64, 256, 0, stream>>>(delta_p, logits);
    wsym_kernel<<<2080, 256, 0, stream>>>(W, Wb);    // 64*65/2 triangular tile pairs

    for (int it = 0; it < NITER; ++it) {
        if (it) update_kernel<<<16, 256, 0, stream>>>(logits);
        matvec_kernel<<<dim3(64, MSPLIT), 256, 0, stream>>>(Wb);
    }
    final_kernel<<<16, 256, 0, stream>>>(logits, out);
}